// Round 5
// baseline (294.384 us; speedup 1.0000x reference)
//
#include <hip/hip_runtime.h>

#define F 128

// ---------- CSR build ----------

__global__ void hist_kernel(const int* __restrict__ row, int* __restrict__ cnt, int e) {
    int i = blockIdx.x * blockDim.x + threadIdx.x;
    if (i < e) atomicAdd(&cnt[row[i]], 1);
}

// per-block inclusive scan of cnt -> scanned, block sums out; also dinv = rsqrt(cnt+1)
__global__ void scan1_kernel(const int* __restrict__ cnt, int* __restrict__ scanned,
                             int* __restrict__ blockSums, float* __restrict__ dinv, int n) {
    __shared__ int tmp[256];
    int i = blockIdx.x * 256 + threadIdx.x;
    int v = (i < n) ? cnt[i] : 0;
    tmp[threadIdx.x] = v;
    __syncthreads();
    #pragma unroll
    for (int off = 1; off < 256; off <<= 1) {
        int t = (threadIdx.x >= off) ? tmp[threadIdx.x - off] : 0;
        __syncthreads();
        tmp[threadIdx.x] += t;
        __syncthreads();
    }
    if (i < n) {
        scanned[i] = tmp[threadIdx.x];
        dinv[i] = rsqrtf((float)(v + 1));   // +1 self loop
    }
    if (threadIdx.x == 255) blockSums[blockIdx.x] = tmp[255];
}

// single-block exclusive scan of block sums (nb <= 256)
__global__ void scan2_kernel(int* __restrict__ blockSums, int nb) {
    __shared__ int tmp[256];
    int v = (threadIdx.x < nb) ? blockSums[threadIdx.x] : 0;
    tmp[threadIdx.x] = v;
    __syncthreads();
    #pragma unroll
    for (int off = 1; off < 256; off <<= 1) {
        int t = (threadIdx.x >= off) ? tmp[threadIdx.x - off] : 0;
        __syncthreads();
        tmp[threadIdx.x] += t;
        __syncthreads();
    }
    if (threadIdx.x < nb) blockSums[threadIdx.x] = tmp[threadIdx.x] - v;  // exclusive
}

// rowStart[i] = inclusive[i] + blockOff - cnt[i]; rowStart[n] = total; cursor init.
// cursor may alias cnt (each i read-then-written by exactly one thread).
__global__ void scan3_kernel(int* __restrict__ rowStart, const int* __restrict__ cnt,
                             const int* __restrict__ blockOff, int* __restrict__ cursor, int n) {
    int i = blockIdx.x * 256 + threadIdx.x;
    if (i >= n) return;
    int inc = rowStart[i] + blockOff[blockIdx.x];
    int start = inc - cnt[i];
    rowStart[i] = start;
    cursor[i] = start;
    if (i == n - 1) rowStart[n] = inc;
}

__global__ void bucket_kernel(const int* __restrict__ row, const int* __restrict__ col,
                              int* __restrict__ cursor, const float* __restrict__ dinv,
                              int* __restrict__ csr_col, float* __restrict__ csr_w, int e) {
    int i = blockIdx.x * blockDim.x + threadIdx.x;
    if (i >= e) return;
    int r = row[i], c = col[i];
    int slot = atomicAdd(&cursor[r], 1);
    csr_col[slot] = c;
    csr_w[slot] = dinv[r] * dinv[c];
}

// W1[128][128]->wt1[128][128], W2[40][128]->wt2[128][40]
__global__ void transpose_both_kernel(const float* __restrict__ W1, const float* __restrict__ W2,
                                      float* __restrict__ wt1, float* __restrict__ wt2) {
    int i = blockIdx.x * blockDim.x + threadIdx.x;
    if (i < F * F) {
        wt1[(i & 127) * F + (i >> 7)] = W1[i];
    } else if (i < F * F + 40 * F) {
        int j = i - F * F;
        wt2[(j & 127) * 40 + (j >> 7)] = W2[j];
    }
}

// ---------- fused layer-1 gather + GEMM1(+relu+bias+alpha2) + GEMM2 -> y ----------
// Block: 256 threads (4 waves), 64 nodes. LDS tile zs reused for z, then h, then y.
__global__ __launch_bounds__(256) void fused_layer_kernel(
    const float* __restrict__ x, const int* __restrict__ rowStart,
    const int* __restrict__ csr_col, const float* __restrict__ csr_w,
    const float* __restrict__ dinv, const float* __restrict__ aw1,
    const float* __restrict__ ab1, const float* __restrict__ wt1,
    const float* __restrict__ b1, const float* __restrict__ aw2,
    const float* __restrict__ ab2, const float* __restrict__ wt2,
    float* __restrict__ y, float* __restrict__ alpha2, int n) {
    constexpr int LD = F + 4;  // 132
    __shared__ float zs[64 * LD];
    int node0 = blockIdx.x * 64;
    int wave = threadIdx.x >> 6;
    int lane = threadIdx.x & 63;

    // ---- Phase A: gather 16 nodes per wave (alpha1 + self-loop + mix) ----
    #pragma unroll 1
    for (int i = 0; i < 16; ++i) {
        int nd = wave * 16 + i;
        int node = node0 + nd;
        if (node < n) {
            float2 xv = ((const float2*)(x + (size_t)node * F))[lane];
            float2 awv = ((const float2*)aw1)[lane];
            float s = xv.x * awv.x + xv.y * awv.y;
            #pragma unroll
            for (int off = 32; off > 0; off >>= 1) s += __shfl_down(s, off);
            s = __shfl(s, 0);
            float a = 1.0f / (1.0f + expf(-(s + ab1[0])));
            float d = dinv[node];
            float2 acc;
            acc.x = d * d * xv.x;
            acc.y = d * d * xv.y;
            int j = rowStart[node], en = rowStart[node + 1];
            for (; j + 3 < en; j += 4) {
                int c0 = csr_col[j], c1 = csr_col[j + 1], c2 = csr_col[j + 2], c3 = csr_col[j + 3];
                float w0 = csr_w[j], w1 = csr_w[j + 1], w2 = csr_w[j + 2], w3 = csr_w[j + 3];
                float2 f0 = ((const float2*)(x + (size_t)c0 * F))[lane];
                float2 f1 = ((const float2*)(x + (size_t)c1 * F))[lane];
                float2 f2 = ((const float2*)(x + (size_t)c2 * F))[lane];
                float2 f3 = ((const float2*)(x + (size_t)c3 * F))[lane];
                acc.x += w0 * f0.x; acc.y += w0 * f0.y;
                acc.x += w1 * f1.x; acc.y += w1 * f1.y;
                acc.x += w2 * f2.x; acc.y += w2 * f2.y;
                acc.x += w3 * f3.x; acc.y += w3 * f3.y;
            }
            for (; j < en; ++j) {
                int c0 = csr_col[j];
                float w0 = csr_w[j];
                float2 f0 = ((const float2*)(x + (size_t)c0 * F))[lane];
                acc.x += w0 * f0.x; acc.y += w0 * f0.y;
            }
            float ca = 1.0f - a, cb = 2.0f * a - 1.0f;
            float2 o;
            o.x = ca * xv.x + cb * acc.x;
            o.y = ca * xv.y + cb * acc.y;
            ((float2*)&zs[nd * LD])[lane] = o;
        } else {
            ((float2*)&zs[nd * LD])[lane] = make_float2(0.f, 0.f);
        }
    }
    __syncthreads();

    // ---- Phase B: h = relu(z @ wt1 + b1); alpha2 = sigmoid(h . aw2 + ab2) ----
    // mt = tid%32 (m-tile of 4), ng = tid/32 (8 node-groups of 8 nodes)
    {
        int mt = threadIdx.x & 31;
        int ng = threadIdx.x >> 5;
        int m0 = mt * 4;
        float4 acc[8];
        #pragma unroll
        for (int i = 0; i < 8; ++i) acc[i] = make_float4(0.f, 0.f, 0.f, 0.f);
        #pragma unroll 2
        for (int kt = 0; kt < F / 4; ++kt) {
            int k = kt * 4;
            float4 w0 = *(const float4*)&wt1[(size_t)(k + 0) * F + m0];
            float4 w1 = *(const float4*)&wt1[(size_t)(k + 1) * F + m0];
            float4 w2 = *(const float4*)&wt1[(size_t)(k + 2) * F + m0];
            float4 w3 = *(const float4*)&wt1[(size_t)(k + 3) * F + m0];
            #pragma unroll
            for (int i = 0; i < 8; ++i) {
                float4 zv = *(const float4*)&zs[(ng * 8 + i) * LD + k];
                acc[i].x += zv.x * w0.x + zv.y * w1.x + zv.z * w2.x + zv.w * w3.x;
                acc[i].y += zv.x * w0.y + zv.y * w1.y + zv.z * w2.y + zv.w * w3.y;
                acc[i].z += zv.x * w0.z + zv.y * w1.z + zv.z * w2.z + zv.w * w3.z;
                acc[i].w += zv.x * w0.w + zv.y * w1.w + zv.z * w2.w + zv.w * w3.w;
            }
        }
        __syncthreads();  // all zs(z) reads done before overwriting with h

        float4 b4 = *(const float4*)&b1[m0];
        float4 awv = *(const float4*)&aw2[m0];
        float asum[8];
        #pragma unroll
        for (int i = 0; i < 8; ++i) {
            float4 o;
            o.x = fmaxf(acc[i].x + b4.x, 0.f);
            o.y = fmaxf(acc[i].y + b4.y, 0.f);
            o.z = fmaxf(acc[i].z + b4.z, 0.f);
            o.w = fmaxf(acc[i].w + b4.w, 0.f);
            asum[i] = o.x * awv.x + o.y * awv.y + o.z * awv.z + o.w * awv.w;
            *(float4*)&zs[(ng * 8 + i) * LD + m0] = o;  // h into LDS
        }
        // alpha2: reduce over the 32 mt-threads (half-wave)
        #pragma unroll
        for (int i = 0; i < 8; ++i) {
            float s = asum[i];
            #pragma unroll
            for (int off = 16; off > 0; off >>= 1) s += __shfl_xor(s, off);
            if (mt == 0) {
                int node = node0 + ng * 8 + i;
                if (node < n) alpha2[node] = 1.0f / (1.0f + expf(-(s + ab2[0])));
            }
        }
    }
    __syncthreads();

    // ---- Phase C: y = h @ wt2  (64 nodes x 40) ----
    {
        int node = threadIdx.x & 63;
        int mg = threadIdx.x >> 6;   // 0..3
        int m0 = mg * 10;
        float acc2[10];
        #pragma unroll
        for (int j = 0; j < 10; ++j) acc2[j] = 0.f;
        #pragma unroll 4
        for (int kt = 0; kt < F / 4; ++kt) {
            float4 zv = *(const float4*)&zs[node * LD + kt * 4];
            const float* wr = wt2 + (size_t)(kt * 4) * 40 + m0;
            #pragma unroll
            for (int jj = 0; jj < 5; ++jj) {
                float2 wa = *(const float2*)&wr[jj * 2];
                float2 wb = *(const float2*)&wr[40 + jj * 2];
                float2 wc = *(const float2*)&wr[80 + jj * 2];
                float2 wd = *(const float2*)&wr[120 + jj * 2];
                acc2[2 * jj]     += zv.x * wa.x + zv.y * wb.x + zv.z * wc.x + zv.w * wd.x;
                acc2[2 * jj + 1] += zv.x * wa.y + zv.y * wb.y + zv.z * wc.y + zv.w * wd.y;
            }
        }
        __syncthreads();  // all h reads done before restaging y
        #pragma unroll
        for (int j = 0; j < 10; ++j) zs[node * 40 + m0 + j] = acc2[j];
    }
    __syncthreads();

    // ---- coalesced y write: 64*40 = 2560 floats = 640 float4 ----
    {
        int base4 = blockIdx.x * 640;          // node0*40/4
        int lim4 = n * 10;                     // n*40/4
        for (int i = threadIdx.x; i < 640; i += 256) {
            int gi4 = base4 + i;
            if (gi4 < lim4) ((float4*)y)[gi4] = *(float4*)&zs[i * 4];
        }
    }
}

// ---------- gather on 40-dim projected features + mix + bias (final output) ----------
__global__ void gather40_kernel(const float* __restrict__ y, const int* __restrict__ rowStart,
                                const int* __restrict__ csr_col, const float* __restrict__ csr_w,
                                const float* __restrict__ dinv, const float* __restrict__ alpha,
                                const float* __restrict__ bias, float* __restrict__ out, int n) {
    int wid = (blockIdx.x * blockDim.x + threadIdx.x) >> 6;
    int lane = threadIdx.x & 63;
    if (wid >= n || lane >= 40) return;
    float yv = y[(size_t)wid * 40 + lane];
    float d = dinv[wid];
    float acc = d * d * yv;
    int j = rowStart[wid], en = rowStart[wid + 1];
    for (; j + 3 < en; j += 4) {
        int c0 = csr_col[j], c1 = csr_col[j + 1], c2 = csr_col[j + 2], c3 = csr_col[j + 3];
        float w0 = csr_w[j], w1 = csr_w[j + 1], w2 = csr_w[j + 2], w3 = csr_w[j + 3];
        acc += w0 * y[(size_t)c0 * 40 + lane];
        acc += w1 * y[(size_t)c1 * 40 + lane];
        acc += w2 * y[(size_t)c2 * 40 + lane];
        acc += w3 * y[(size_t)c3 * 40 + lane];
    }
    for (; j < en; ++j) {
        acc += csr_w[j] * y[(size_t)csr_col[j] * 40 + lane];
    }
    float a = alpha[wid];
    out[(size_t)wid * 40 + lane] = (1.0f - a) * yv + (2.0f * a - 1.0f) * acc + bias[lane];
}

extern "C" void kernel_launch(void* const* d_in, const int* in_sizes, int n_in,
                              void* d_out, int out_size, void* d_ws, size_t ws_size,
                              hipStream_t stream) {
    const float* x   = (const float*)d_in[0];
    const int*   ei  = (const int*)d_in[1];
    const float* aw1 = (const float*)d_in[2];
    const float* ab1 = (const float*)d_in[3];
    const float* W1  = (const float*)d_in[4];
    const float* b1  = (const float*)d_in[5];
    const float* aw2 = (const float*)d_in[6];
    const float* ab2 = (const float*)d_in[7];
    const float* W2  = (const float*)d_in[8];
    const float* b2  = (const float*)d_in[9];
    float* out = (float*)d_out;

    int n = in_sizes[0] / F;   // 50000
    int e = in_sizes[1] / 2;   // 600000
    const int* row = ei;
    const int* col = ei + e;

    // workspace layout (4B elements)
    char* p = (char*)d_ws;
    int*   cnt      = (int*)p;            p += (size_t)n * 4;        // reused as cursor
    int*   rowStart = (int*)p;            p += (size_t)(n + 2) * 4;
    int*   blockSums= (int*)p;            p += 256 * 4;
    int*   csr_col  = (int*)p;            p += (size_t)e * 4;
    float* dinv     = (float*)p;          p += (size_t)n * 4;
    float* csr_w    = (float*)p;          p += (size_t)e * 4;
    float* wt1      = (float*)p;          p += (size_t)F * F * 4;    // wt1[128][128]
    float* wt2      = (float*)p;          p += (size_t)F * 40 * 4;   // wt2[128][40]
    float* ybuf     = (float*)p;          p += (size_t)n * 40 * 4;
    float* alpha2   = (float*)p;

    int nb = (n + 255) / 256;  // 196 <= 256

    // ---- CSR build (shared by both layers) + W transposes ----
    hipMemsetAsync(cnt, 0, (size_t)n * 4, stream);
    hist_kernel<<<(e + 255) / 256, 256, 0, stream>>>(row, cnt, e);
    scan1_kernel<<<nb, 256, 0, stream>>>(cnt, rowStart, blockSums, dinv, n);
    scan2_kernel<<<1, 256, 0, stream>>>(blockSums, nb);
    scan3_kernel<<<nb, 256, 0, stream>>>(rowStart, cnt, blockSums, cnt, n);  // cursor aliases cnt
    bucket_kernel<<<(e + 255) / 256, 256, 0, stream>>>(row, col, cnt, dinv, csr_col, csr_w, e);
    transpose_both_kernel<<<(F * F + 40 * F + 255) / 256, 256, 0, stream>>>(W1, W2, wt1, wt2);

    int gblk = (n + 63) / 64;  // 782

    // ---- fused layer 1 + projection of layer 2 ----
    fused_layer_kernel<<<gblk, 256, 0, stream>>>(x, rowStart, csr_col, csr_w, dinv,
                                                 aw1, ab1, wt1, b1, aw2, ab2, wt2,
                                                 ybuf, alpha2, n);

    // ---- layer 2 mix on 40-dim ----
    gather40_kernel<<<(n + 3) / 4, 256, 0, stream>>>(ybuf, rowStart, csr_col, csr_w, dinv,
                                                     alpha2, b2, out, n);
}

// Round 6
// 235.482 us; speedup vs baseline: 1.2501x; 1.2501x over previous
//
#include <hip/hip_runtime.h>

#define F 128

// ---------- bf16 helpers ----------
__device__ inline unsigned int f2bf(float f) {
    union { float f; unsigned int u; } c; c.f = f;
    return (c.u + 0x7fffu + ((c.u >> 16) & 1u)) >> 16;   // RNE
}
__device__ inline float2 bf2_to_f2(unsigned int v) {
    union { unsigned int u; float f; } a, b;
    a.u = (v & 0xffffu) << 16;
    b.u = v & 0xffff0000u;
    return make_float2(a.f, b.f);
}

// ---------- CSR build ----------

__global__ void hist_kernel(const int* __restrict__ row, int* __restrict__ cnt, int e) {
    int i = blockIdx.x * blockDim.x + threadIdx.x;
    if (i < e) atomicAdd(&cnt[row[i]], 1);
}

// per-block inclusive scan of cnt -> scanned, block sums out; also dinv = rsqrt(cnt+1)
__global__ void scan1_kernel(const int* __restrict__ cnt, int* __restrict__ scanned,
                             int* __restrict__ blockSums, float* __restrict__ dinv, int n) {
    __shared__ int tmp[256];
    int i = blockIdx.x * 256 + threadIdx.x;
    int v = (i < n) ? cnt[i] : 0;
    tmp[threadIdx.x] = v;
    __syncthreads();
    #pragma unroll
    for (int off = 1; off < 256; off <<= 1) {
        int t = (threadIdx.x >= off) ? tmp[threadIdx.x - off] : 0;
        __syncthreads();
        tmp[threadIdx.x] += t;
        __syncthreads();
    }
    if (i < n) {
        scanned[i] = tmp[threadIdx.x];
        dinv[i] = rsqrtf((float)(v + 1));   // +1 self loop
    }
    if (threadIdx.x == 255) blockSums[blockIdx.x] = tmp[255];
}

// single-block exclusive scan of block sums (nb <= 256)
__global__ void scan2_kernel(int* __restrict__ blockSums, int nb) {
    __shared__ int tmp[256];
    int v = (threadIdx.x < nb) ? blockSums[threadIdx.x] : 0;
    tmp[threadIdx.x] = v;
    __syncthreads();
    #pragma unroll
    for (int off = 1; off < 256; off <<= 1) {
        int t = (threadIdx.x >= off) ? tmp[threadIdx.x - off] : 0;
        __syncthreads();
        tmp[threadIdx.x] += t;
        __syncthreads();
    }
    if (threadIdx.x < nb) blockSums[threadIdx.x] = tmp[threadIdx.x] - v;  // exclusive
}

// rowStart[i] = inclusive[i] + blockOff - cnt[i]; rowStart[n] = total; cursor init.
__global__ void scan3_kernel(int* __restrict__ rowStart, const int* __restrict__ cnt,
                             const int* __restrict__ blockOff, int* __restrict__ cursor, int n) {
    int i = blockIdx.x * 256 + threadIdx.x;
    if (i >= n) return;
    int inc = rowStart[i] + blockOff[blockIdx.x];
    int start = inc - cnt[i];
    rowStart[i] = start;
    cursor[i] = start;
    if (i == n - 1) rowStart[n] = inc;
}

__global__ void bucket_kernel(const int* __restrict__ row, const int* __restrict__ col,
                              int* __restrict__ cursor, const float* __restrict__ dinv,
                              int* __restrict__ csr_col, float* __restrict__ csr_w, int e) {
    int i = blockIdx.x * blockDim.x + threadIdx.x;
    if (i >= e) return;
    int r = row[i], c = col[i];
    int slot = atomicAdd(&cursor[r], 1);
    csr_col[slot] = c;
    csr_w[slot] = dinv[r] * dinv[c];
}

// W1[128][128]->wt1[128][128], W2[40][128]->wt2[128][40]
__global__ void transpose_both_kernel(const float* __restrict__ W1, const float* __restrict__ W2,
                                      float* __restrict__ wt1, float* __restrict__ wt2) {
    int i = blockIdx.x * blockDim.x + threadIdx.x;
    if (i < F * F) {
        wt1[(i & 127) * F + (i >> 7)] = W1[i];
    } else if (i < F * F + 40 * F) {
        int j = i - F * F;
        wt2[(j & 127) * 40 + (j >> 7)] = W2[j];
    }
}

// x[n][128] fp32 -> xbf[n][64] packed bf16 pairs
__global__ void convert_bf_kernel(const float* __restrict__ x, unsigned int* __restrict__ xbf,
                                  int total64) {
    int i = blockIdx.x * blockDim.x + threadIdx.x;
    if (i >= total64) return;
    float2 v = ((const float2*)x)[i];
    xbf[i] = f2bf(v.x) | (f2bf(v.y) << 16);
}

// ---------- fused alpha + gather + self-loop + mix (128-dim, bf16 neighbor reads) ----------
// one wave per node; lane covers features {2*lane, 2*lane+1}
__global__ void gather_kernel(const float* __restrict__ feat, const unsigned int* __restrict__ featbf,
                              const int* __restrict__ rowStart,
                              const int* __restrict__ csr_col, const float* __restrict__ csr_w,
                              const float* __restrict__ dinv, const float* __restrict__ aw,
                              const float* __restrict__ ab, float* __restrict__ z, int n) {
    int wid = (blockIdx.x * blockDim.x + threadIdx.x) >> 6;
    int lane = threadIdx.x & 63;
    if (wid >= n) return;
    float2 xv = ((const float2*)(feat + (size_t)wid * F))[lane];
    float2 awv = ((const float2*)aw)[lane];
    // alpha = sigmoid(x . aw + ab)
    float s = xv.x * awv.x + xv.y * awv.y;
    #pragma unroll
    for (int off = 32; off > 0; off >>= 1) s += __shfl_down(s, off);
    s = __shfl(s, 0);
    float a = 1.0f / (1.0f + expf(-(s + ab[0])));
    // self loop (fp32)
    float d = dinv[wid];
    float2 acc;
    acc.x = d * d * xv.x;
    acc.y = d * d * xv.y;
    // neighbors (bf16 rows, 4-edge unroll)
    int j = rowStart[wid], en = rowStart[wid + 1];
    for (; j + 3 < en; j += 4) {
        int c0 = csr_col[j], c1 = csr_col[j + 1], c2 = csr_col[j + 2], c3 = csr_col[j + 3];
        float w0 = csr_w[j], w1 = csr_w[j + 1], w2 = csr_w[j + 2], w3 = csr_w[j + 3];
        float2 f0 = bf2_to_f2(featbf[(size_t)c0 * 64 + lane]);
        float2 f1 = bf2_to_f2(featbf[(size_t)c1 * 64 + lane]);
        float2 f2 = bf2_to_f2(featbf[(size_t)c2 * 64 + lane]);
        float2 f3 = bf2_to_f2(featbf[(size_t)c3 * 64 + lane]);
        acc.x += w0 * f0.x; acc.y += w0 * f0.y;
        acc.x += w1 * f1.x; acc.y += w1 * f1.y;
        acc.x += w2 * f2.x; acc.y += w2 * f2.y;
        acc.x += w3 * f3.x; acc.y += w3 * f3.y;
    }
    for (; j < en; ++j) {
        int c0 = csr_col[j];
        float w0 = csr_w[j];
        float2 f0 = bf2_to_f2(featbf[(size_t)c0 * 64 + lane]);
        acc.x += w0 * f0.x; acc.y += w0 * f0.y;
    }
    // z = (1-a)*x + (2a-1)*z_lp
    float ca = 1.0f - a, cb = 2.0f * a - 1.0f;
    float2 o;
    o.x = ca * xv.x + cb * acc.x;
    o.y = ca * xv.y + cb * acc.y;
    ((float2*)(z + (size_t)wid * F))[lane] = o;
}

// ---------- gather on 40-dim projected features + mix + bias (final output) ----------
__global__ void gather40_kernel(const float* __restrict__ y, const int* __restrict__ rowStart,
                                const int* __restrict__ csr_col, const float* __restrict__ csr_w,
                                const float* __restrict__ dinv, const float* __restrict__ alpha,
                                const float* __restrict__ bias, float* __restrict__ out, int n) {
    int wid = (blockIdx.x * blockDim.x + threadIdx.x) >> 6;
    int lane = threadIdx.x & 63;
    if (wid >= n || lane >= 40) return;
    float yv = y[(size_t)wid * 40 + lane];
    float d = dinv[wid];
    float acc = d * d * yv;
    int j = rowStart[wid], en = rowStart[wid + 1];
    for (; j + 3 < en; j += 4) {
        int c0 = csr_col[j], c1 = csr_col[j + 1], c2 = csr_col[j + 2], c3 = csr_col[j + 3];
        float w0 = csr_w[j], w1 = csr_w[j + 1], w2 = csr_w[j + 2], w3 = csr_w[j + 3];
        acc += w0 * y[(size_t)c0 * 40 + lane];
        acc += w1 * y[(size_t)c1 * 40 + lane];
        acc += w2 * y[(size_t)c2 * 40 + lane];
        acc += w3 * y[(size_t)c3 * 40 + lane];
    }
    for (; j < en; ++j) {
        acc += csr_w[j] * y[(size_t)csr_col[j] * 40 + lane];
    }
    float a = alpha[wid];
    out[(size_t)wid * 40 + lane] = (1.0f - a) * yv + (2.0f * a - 1.0f) * acc + bias[lane];
}

// ---------- dense layers (register-tiled) ----------
// out[n][m] = sum_k Z[n][k]*Wt[k][m] (+ bias[m]) (+ ReLU)
// If ALPHA: also emits alphaOut[node] = sigmoid(out_row . aw + ab) (requires MT==32).
template <int M, int MT, int NPG, bool RELU, bool BIAS, bool ALPHA>
__global__ void gemm_kernel(const float* __restrict__ Z, const float* __restrict__ Wt,
                            const float* __restrict__ bias, float* __restrict__ out,
                            const float* __restrict__ aw, const float* __restrict__ ab,
                            float* __restrict__ alphaOut, int n) {
    constexpr int NODES = 64;
    constexpr int LD = F + 4;  // 132 floats: row stride 528B (b128-aligned, bank-skewed)
    __shared__ float zs[NODES * LD];
    int node0 = blockIdx.x * NODES;
    for (int i = threadIdx.x; i < NODES * (F / 4); i += blockDim.x) {
        int nd = i >> 5, f4 = i & 31;
        float4 v = make_float4(0.f, 0.f, 0.f, 0.f);
        if (node0 + nd < n) v = ((const float4*)(Z + (size_t)(node0 + nd) * F))[f4];
        *(float4*)&zs[nd * LD + f4 * 4] = v;
    }
    __syncthreads();

    int mt = threadIdx.x % MT;
    int ng = threadIdx.x / MT;
    int m0 = mt * 4;

    float4 acc[NPG];
    #pragma unroll
    for (int i = 0; i < NPG; ++i) acc[i] = make_float4(0.f, 0.f, 0.f, 0.f);

    #pragma unroll 2
    for (int kt = 0; kt < F / 4; ++kt) {
        int k = kt * 4;
        float4 w0 = *(const float4*)&Wt[(size_t)(k + 0) * M + m0];
        float4 w1 = *(const float4*)&Wt[(size_t)(k + 1) * M + m0];
        float4 w2 = *(const float4*)&Wt[(size_t)(k + 2) * M + m0];
        float4 w3 = *(const float4*)&Wt[(size_t)(k + 3) * M + m0];
        #pragma unroll
        for (int i = 0; i < NPG; ++i) {
            float4 zv = *(const float4*)&zs[(ng * NPG + i) * LD + k];
            acc[i].x += zv.x * w0.x + zv.y * w1.x + zv.z * w2.x + zv.w * w3.x;
            acc[i].y += zv.x * w0.y + zv.y * w1.y + zv.z * w2.y + zv.w * w3.y;
            acc[i].z += zv.x * w0.z + zv.y * w1.z + zv.z * w2.z + zv.w * w3.z;
            acc[i].w += zv.x * w0.w + zv.y * w1.w + zv.z * w2.w + zv.w * w3.w;
        }
    }

    float4 b4 = make_float4(0.f, 0.f, 0.f, 0.f);
    if (BIAS) b4 = *(const float4*)&bias[m0];
    float4 awv = make_float4(0.f, 0.f, 0.f, 0.f);
    if (ALPHA) awv = *(const float4*)&aw[m0];
    float asum[NPG];

    #pragma unroll
    for (int i = 0; i < NPG; ++i) {
        int node = node0 + ng * NPG + i;
        float4 o;
        o.x = acc[i].x + b4.x; o.y = acc[i].y + b4.y;
        o.z = acc[i].z + b4.z; o.w = acc[i].w + b4.w;
        if (RELU) {
            o.x = fmaxf(o.x, 0.f); o.y = fmaxf(o.y, 0.f);
            o.z = fmaxf(o.z, 0.f); o.w = fmaxf(o.w, 0.f);
        }
        if (ALPHA) asum[i] = o.x * awv.x + o.y * awv.y + o.z * awv.z + o.w * awv.w;
        if (node < n) *(float4*)&out[(size_t)node * M + m0] = o;
    }

    if (ALPHA) {
        #pragma unroll
        for (int i = 0; i < NPG; ++i) {
            float s = asum[i];
            #pragma unroll
            for (int off = 16; off > 0; off >>= 1) s += __shfl_xor(s, off);
            if (mt == 0) {
                int node = node0 + ng * NPG + i;
                if (node < n) alphaOut[node] = 1.0f / (1.0f + expf(-(s + ab[0])));
            }
        }
    }
}

extern "C" void kernel_launch(void* const* d_in, const int* in_sizes, int n_in,
                              void* d_out, int out_size, void* d_ws, size_t ws_size,
                              hipStream_t stream) {
    const float* x   = (const float*)d_in[0];
    const int*   ei  = (const int*)d_in[1];
    const float* aw1 = (const float*)d_in[2];
    const float* ab1 = (const float*)d_in[3];
    const float* W1  = (const float*)d_in[4];
    const float* b1  = (const float*)d_in[5];
    const float* aw2 = (const float*)d_in[6];
    const float* ab2 = (const float*)d_in[7];
    const float* W2  = (const float*)d_in[8];
    const float* b2  = (const float*)d_in[9];
    float* out = (float*)d_out;

    int n = in_sizes[0] / F;   // 50000
    int e = in_sizes[1] / 2;   // 600000
    const int* row = ei;
    const int* col = ei + e;

    // workspace layout (4B elements)
    char* p = (char*)d_ws;
    int*   cnt      = (int*)p;            p += (size_t)n * 4;        // reused as cursor
    int*   rowStart = (int*)p;            p += (size_t)(n + 2) * 4;
    int*   blockSums= (int*)p;            p += 256 * 4;
    int*   csr_col  = (int*)p;            p += (size_t)e * 4;
    float* dinv     = (float*)p;          p += (size_t)n * 4;
    float* csr_w    = (float*)p;          p += (size_t)e * 4;
    float* wt1      = (float*)p;          p += (size_t)F * F * 4;    // wt1[128][128]
    float* wt2      = (float*)p;          p += (size_t)F * 40 * 4;   // wt2[128][40]
    unsigned int* xbf = (unsigned int*)p; p += (size_t)n * 64 * 4;   // bf16-packed x
    float* zlp      = (float*)p;          p += (size_t)n * F * 4;    // z (layer1) / y (layer2)
    float* hbuf     = (float*)p;          p += (size_t)n * F * 4;
    float* alpha2   = (float*)p;

    int nb = (n + 255) / 256;  // 196 <= 256

    // ---- CSR build (shared by both layers) + W transposes + bf16 copy ----
    hipMemsetAsync(cnt, 0, (size_t)n * 4, stream);
    hist_kernel<<<(e + 255) / 256, 256, 0, stream>>>(row, cnt, e);
    scan1_kernel<<<nb, 256, 0, stream>>>(cnt, rowStart, blockSums, dinv, n);
    scan2_kernel<<<1, 256, 0, stream>>>(blockSums, nb);
    scan3_kernel<<<nb, 256, 0, stream>>>(rowStart, cnt, blockSums, cnt, n);  // cursor aliases cnt
    bucket_kernel<<<(e + 255) / 256, 256, 0, stream>>>(row, col, cnt, dinv, csr_col, csr_w, e);
    transpose_both_kernel<<<(F * F + 40 * F + 255) / 256, 256, 0, stream>>>(W1, W2, wt1, wt2);
    convert_bf_kernel<<<(n * 64 + 255) / 256, 256, 0, stream>>>(x, xbf, n * 64);

    int gblk = (n + 63) / 64;  // 782

    // ---- layer 1: gather(x) -> z; h = relu(z@wt1 + b1); alpha2 = sigmoid(h.aw2+ab2) ----
    gather_kernel<<<(n + 3) / 4, 256, 0, stream>>>(x, xbf, rowStart, csr_col, csr_w, dinv,
                                                   aw1, ab1, zlp, n);
    gemm_kernel<128, 32, 8, true, true, true><<<gblk, 256, 0, stream>>>(
        zlp, wt1, b1, hbuf, aw2, ab2, alpha2, n);

    // ---- layer 2 (reordered): y = h@wt2; out = mix_rows(y) + b2 ----
    float* ybuf = zlp;  // reuse
    gemm_kernel<40, 10, 2, false, false, false><<<gblk, 320, 0, stream>>>(
        hbuf, wt2, nullptr, ybuf, nullptr, nullptr, nullptr, n);
    gather40_kernel<<<(n + 3) / 4, 256, 0, stream>>>(ybuf, rowStart, csr_col, csr_w, dinv,
                                                     alpha2, b2, out, n);
}

// Round 7
// 226.468 us; speedup vs baseline: 1.2999x; 1.0398x over previous
//
#include <hip/hip_runtime.h>

#define F 128

// ---------- bf16 helpers ----------
__device__ inline unsigned int f2bf(float f) {
    union { float f; unsigned int u; } c; c.f = f;
    return (c.u + 0x7fffu + ((c.u >> 16) & 1u)) >> 16;   // RNE
}
__device__ inline float2 bf2_to_f2(unsigned int v) {
    union { unsigned int u; float f; } a, b;
    a.u = (v & 0xffffu) << 16;
    b.u = v & 0xffff0000u;
    return make_float2(a.f, b.f);
}

// ---------- CSR build ----------

__global__ void hist_kernel(const int* __restrict__ row, int* __restrict__ cnt, int e) {
    int i = blockIdx.x * blockDim.x + threadIdx.x;
    if (i < e) atomicAdd(&cnt[row[i]], 1);
}

// per-block inclusive scan of cnt -> scanned, block sums out; also dinv = rsqrt(cnt+1)
__global__ void scan1_kernel(const int* __restrict__ cnt, int* __restrict__ scanned,
                             int* __restrict__ blockSums, float* __restrict__ dinv, int n) {
    __shared__ int tmp[256];
    int i = blockIdx.x * 256 + threadIdx.x;
    int v = (i < n) ? cnt[i] : 0;
    tmp[threadIdx.x] = v;
    __syncthreads();
    #pragma unroll
    for (int off = 1; off < 256; off <<= 1) {
        int t = (threadIdx.x >= off) ? tmp[threadIdx.x - off] : 0;
        __syncthreads();
        tmp[threadIdx.x] += t;
        __syncthreads();
    }
    if (i < n) {
        scanned[i] = tmp[threadIdx.x];
        dinv[i] = rsqrtf((float)(v + 1));   // +1 self loop
    }
    if (threadIdx.x == 255) blockSums[blockIdx.x] = tmp[255];
}

// single-block exclusive scan of block sums (nb <= 256)
__global__ void scan2_kernel(int* __restrict__ blockSums, int nb) {
    __shared__ int tmp[256];
    int v = (threadIdx.x < nb) ? blockSums[threadIdx.x] : 0;
    tmp[threadIdx.x] = v;
    __syncthreads();
    #pragma unroll
    for (int off = 1; off < 256; off <<= 1) {
        int t = (threadIdx.x >= off) ? tmp[threadIdx.x - off] : 0;
        __syncthreads();
        tmp[threadIdx.x] += t;
        __syncthreads();
    }
    if (threadIdx.x < nb) blockSums[threadIdx.x] = tmp[threadIdx.x] - v;  // exclusive
}

// rowStart[i] = inclusive[i] + blockOff - cnt[i]; rowStart[n] = total; cursor init.
__global__ void scan3_kernel(int* __restrict__ rowStart, const int* __restrict__ cnt,
                             const int* __restrict__ blockOff, int* __restrict__ cursor, int n) {
    int i = blockIdx.x * 256 + threadIdx.x;
    if (i >= n) return;
    int inc = rowStart[i] + blockOff[blockIdx.x];
    int start = inc - cnt[i];
    rowStart[i] = start;
    cursor[i] = start;
    if (i == n - 1) rowStart[n] = inc;
}

// packed CSR entry: {col, weight} in one 8B store (one cacheline touched per edge)
__global__ void bucket_kernel(const int* __restrict__ row, const int* __restrict__ col,
                              int* __restrict__ cursor, const float* __restrict__ dinv,
                              int2* __restrict__ csr_cw, int e) {
    int i = blockIdx.x * blockDim.x + threadIdx.x;
    if (i >= e) return;
    int r = row[i], c = col[i];
    int slot = atomicAdd(&cursor[r], 1);
    float w = dinv[r] * dinv[c];
    csr_cw[slot] = make_int2(c, __float_as_int(w));
}

// W1[128][128]->wt1[128][128], W2[40][128]->wt2[128][40]
__global__ void transpose_both_kernel(const float* __restrict__ W1, const float* __restrict__ W2,
                                      float* __restrict__ wt1, float* __restrict__ wt2) {
    int i = blockIdx.x * blockDim.x + threadIdx.x;
    if (i < F * F) {
        wt1[(i & 127) * F + (i >> 7)] = W1[i];
    } else if (i < F * F + 40 * F) {
        int j = i - F * F;
        wt2[(j & 127) * 40 + (j >> 7)] = W2[j];
    }
}

// x[n][128] fp32 -> xbf[n][64] packed bf16 pairs
__global__ void convert_bf_kernel(const float* __restrict__ x, unsigned int* __restrict__ xbf,
                                  int total64) {
    int i = blockIdx.x * blockDim.x + threadIdx.x;
    if (i >= total64) return;
    float2 v = ((const float2*)x)[i];
    xbf[i] = f2bf(v.x) | (f2bf(v.y) << 16);
}

// ---------- fused alpha + gather + self-loop + mix (128-dim, bf16 neighbor reads) ----------
// one wave per node; lane covers features {2*lane, 2*lane+1}
__global__ void gather_kernel(const float* __restrict__ feat, const unsigned int* __restrict__ featbf,
                              const int* __restrict__ rowStart, const int2* __restrict__ csr_cw,
                              const float* __restrict__ dinv, const float* __restrict__ aw,
                              const float* __restrict__ ab, float* __restrict__ z, int n) {
    int wid = (blockIdx.x * blockDim.x + threadIdx.x) >> 6;
    int lane = threadIdx.x & 63;
    if (wid >= n) return;
    float2 xv = ((const float2*)(feat + (size_t)wid * F))[lane];
    float2 awv = ((const float2*)aw)[lane];
    // alpha = sigmoid(x . aw + ab)
    float s = xv.x * awv.x + xv.y * awv.y;
    #pragma unroll
    for (int off = 32; off > 0; off >>= 1) s += __shfl_down(s, off);
    s = __shfl(s, 0);
    float a = 1.0f / (1.0f + expf(-(s + ab[0])));
    // self loop (fp32)
    float d = dinv[wid];
    float2 acc;
    acc.x = d * d * xv.x;
    acc.y = d * d * xv.y;
    // neighbors (bf16 rows, 4-edge unroll)
    int j = rowStart[wid], en = rowStart[wid + 1];
    for (; j + 3 < en; j += 4) {
        int2 cw0 = csr_cw[j], cw1 = csr_cw[j + 1], cw2 = csr_cw[j + 2], cw3 = csr_cw[j + 3];
        float w0 = __int_as_float(cw0.y), w1 = __int_as_float(cw1.y);
        float w2 = __int_as_float(cw2.y), w3 = __int_as_float(cw3.y);
        float2 f0 = bf2_to_f2(featbf[(size_t)cw0.x * 64 + lane]);
        float2 f1 = bf2_to_f2(featbf[(size_t)cw1.x * 64 + lane]);
        float2 f2 = bf2_to_f2(featbf[(size_t)cw2.x * 64 + lane]);
        float2 f3 = bf2_to_f2(featbf[(size_t)cw3.x * 64 + lane]);
        acc.x += w0 * f0.x; acc.y += w0 * f0.y;
        acc.x += w1 * f1.x; acc.y += w1 * f1.y;
        acc.x += w2 * f2.x; acc.y += w2 * f2.y;
        acc.x += w3 * f3.x; acc.y += w3 * f3.y;
    }
    for (; j < en; ++j) {
        int2 cw = csr_cw[j];
        float w0 = __int_as_float(cw.y);
        float2 f0 = bf2_to_f2(featbf[(size_t)cw.x * 64 + lane]);
        acc.x += w0 * f0.x; acc.y += w0 * f0.y;
    }
    // z = (1-a)*x + (2a-1)*z_lp
    float ca = 1.0f - a, cb = 2.0f * a - 1.0f;
    float2 o;
    o.x = ca * xv.x + cb * acc.x;
    o.y = ca * xv.y + cb * acc.y;
    ((float2*)(z + (size_t)wid * F))[lane] = o;
}

// ---------- gather on 40-dim projected features + mix + bias (final output) ----------
__global__ void gather40_kernel(const float* __restrict__ y, const int* __restrict__ rowStart,
                                const int2* __restrict__ csr_cw,
                                const float* __restrict__ dinv, const float* __restrict__ alpha,
                                const float* __restrict__ bias, float* __restrict__ out, int n) {
    int wid = (blockIdx.x * blockDim.x + threadIdx.x) >> 6;
    int lane = threadIdx.x & 63;
    if (wid >= n || lane >= 40) return;
    float yv = y[(size_t)wid * 40 + lane];
    float d = dinv[wid];
    float acc = d * d * yv;
    int j = rowStart[wid], en = rowStart[wid + 1];
    for (; j + 3 < en; j += 4) {
        int2 cw0 = csr_cw[j], cw1 = csr_cw[j + 1], cw2 = csr_cw[j + 2], cw3 = csr_cw[j + 3];
        acc += __int_as_float(cw0.y) * y[(size_t)cw0.x * 40 + lane];
        acc += __int_as_float(cw1.y) * y[(size_t)cw1.x * 40 + lane];
        acc += __int_as_float(cw2.y) * y[(size_t)cw2.x * 40 + lane];
        acc += __int_as_float(cw3.y) * y[(size_t)cw3.x * 40 + lane];
    }
    for (; j < en; ++j) {
        int2 cw = csr_cw[j];
        acc += __int_as_float(cw.y) * y[(size_t)cw.x * 40 + lane];
    }
    float a = alpha[wid];
    out[(size_t)wid * 40 + lane] = (1.0f - a) * yv + (2.0f * a - 1.0f) * acc + bias[lane];
}

// ---------- dense layers (register-tiled) ----------
// out[n][m] = sum_k Z[n][k]*Wt[k][m] (+ bias[m]) (+ ReLU)
// If ALPHA: also emits alphaOut[node] = sigmoid(out_row . aw + ab) (requires MT==32).
template <int M, int MT, int NPG, bool RELU, bool BIAS, bool ALPHA>
__global__ void gemm_kernel(const float* __restrict__ Z, const float* __restrict__ Wt,
                            const float* __restrict__ bias, float* __restrict__ out,
                            const float* __restrict__ aw, const float* __restrict__ ab,
                            float* __restrict__ alphaOut, int n) {
    constexpr int NODES = 64;
    constexpr int LD = F + 4;  // 132 floats: row stride 528B (b128-aligned, bank-skewed)
    __shared__ float zs[NODES * LD];
    int node0 = blockIdx.x * NODES;
    for (int i = threadIdx.x; i < NODES * (F / 4); i += blockDim.x) {
        int nd = i >> 5, f4 = i & 31;
        float4 v = make_float4(0.f, 0.f, 0.f, 0.f);
        if (node0 + nd < n) v = ((const float4*)(Z + (size_t)(node0 + nd) * F))[f4];
        *(float4*)&zs[nd * LD + f4 * 4] = v;
    }
    __syncthreads();

    int mt = threadIdx.x % MT;
    int ng = threadIdx.x / MT;
    int m0 = mt * 4;

    float4 acc[NPG];
    #pragma unroll
    for (int i = 0; i < NPG; ++i) acc[i] = make_float4(0.f, 0.f, 0.f, 0.f);

    #pragma unroll 2
    for (int kt = 0; kt < F / 4; ++kt) {
        int k = kt * 4;
        float4 w0 = *(const float4*)&Wt[(size_t)(k + 0) * M + m0];
        float4 w1 = *(const float4*)&Wt[(size_t)(k + 1) * M + m0];
        float4 w2 = *(const float4*)&Wt[(size_t)(k + 2) * M + m0];
        float4 w3 = *(const float4*)&Wt[(size_t)(k + 3) * M + m0];
        #pragma unroll
        for (int i = 0; i < NPG; ++i) {
            float4 zv = *(const float4*)&zs[(ng * NPG + i) * LD + k];
            acc[i].x += zv.x * w0.x + zv.y * w1.x + zv.z * w2.x + zv.w * w3.x;
            acc[i].y += zv.x * w0.y + zv.y * w1.y + zv.z * w2.y + zv.w * w3.y;
            acc[i].z += zv.x * w0.z + zv.y * w1.z + zv.z * w2.z + zv.w * w3.z;
            acc[i].w += zv.x * w0.w + zv.y * w1.w + zv.z * w2.w + zv.w * w3.w;
        }
    }

    float4 b4 = make_float4(0.f, 0.f, 0.f, 0.f);
    if (BIAS) b4 = *(const float4*)&bias[m0];
    float4 awv = make_float4(0.f, 0.f, 0.f, 0.f);
    if (ALPHA) awv = *(const float4*)&aw[m0];
    float asum[NPG];

    #pragma unroll
    for (int i = 0; i < NPG; ++i) {
        int node = node0 + ng * NPG + i;
        float4 o;
        o.x = acc[i].x + b4.x; o.y = acc[i].y + b4.y;
        o.z = acc[i].z + b4.z; o.w = acc[i].w + b4.w;
        if (RELU) {
            o.x = fmaxf(o.x, 0.f); o.y = fmaxf(o.y, 0.f);
            o.z = fmaxf(o.z, 0.f); o.w = fmaxf(o.w, 0.f);
        }
        if (ALPHA) asum[i] = o.x * awv.x + o.y * awv.y + o.z * awv.z + o.w * awv.w;
        if (node < n) *(float4*)&out[(size_t)node * M + m0] = o;
    }

    if (ALPHA) {
        #pragma unroll
        for (int i = 0; i < NPG; ++i) {
            float s = asum[i];
            #pragma unroll
            for (int off = 16; off > 0; off >>= 1) s += __shfl_xor(s, off);
            if (mt == 0) {
                int node = node0 + ng * NPG + i;
                if (node < n) alphaOut[node] = 1.0f / (1.0f + expf(-(s + ab[0])));
            }
        }
    }
}

extern "C" void kernel_launch(void* const* d_in, const int* in_sizes, int n_in,
                              void* d_out, int out_size, void* d_ws, size_t ws_size,
                              hipStream_t stream) {
    const float* x   = (const float*)d_in[0];
    const int*   ei  = (const int*)d_in[1];
    const float* aw1 = (const float*)d_in[2];
    const float* ab1 = (const float*)d_in[3];
    const float* W1  = (const float*)d_in[4];
    const float* b1  = (const float*)d_in[5];
    const float* aw2 = (const float*)d_in[6];
    const float* ab2 = (const float*)d_in[7];
    const float* W2  = (const float*)d_in[8];
    const float* b2  = (const float*)d_in[9];
    float* out = (float*)d_out;

    int n = in_sizes[0] / F;   // 50000
    int e = in_sizes[1] / 2;   // 600000
    const int* row = ei;
    const int* col = ei + e;

    // workspace layout (4B elements)
    char* p = (char*)d_ws;
    int*   cnt      = (int*)p;            p += (size_t)n * 4;        // reused as cursor
    int*   rowStart = (int*)p;            p += (size_t)(n + 2) * 4;
    int*   blockSums= (int*)p;            p += 256 * 4;
    float* dinv     = (float*)p;          p += (size_t)n * 4;
    int2*  csr_cw   = (int2*)p;           p += (size_t)e * 8;        // packed {col, w}
    float* wt1      = (float*)p;          p += (size_t)F * F * 4;    // wt1[128][128]
    float* wt2      = (float*)p;          p += (size_t)F * 40 * 4;   // wt2[128][40]
    unsigned int* xbf = (unsigned int*)p; p += (size_t)n * 64 * 4;   // bf16-packed x
    float* zlp      = (float*)p;          p += (size_t)n * F * 4;    // z (layer1) / y (layer2)
    float* hbuf     = (float*)p;          p += (size_t)n * F * 4;
    float* alpha2   = (float*)p;

    int nb = (n + 255) / 256;  // 196 <= 256

    // ---- CSR build (shared by both layers) + W transposes + bf16 copy ----
    hipMemsetAsync(cnt, 0, (size_t)n * 4, stream);
    hist_kernel<<<(e + 255) / 256, 256, 0, stream>>>(row, cnt, e);
    scan1_kernel<<<nb, 256, 0, stream>>>(cnt, rowStart, blockSums, dinv, n);
    scan2_kernel<<<1, 256, 0, stream>>>(blockSums, nb);
    scan3_kernel<<<nb, 256, 0, stream>>>(rowStart, cnt, blockSums, cnt, n);  // cursor aliases cnt
    bucket_kernel<<<(e + 255) / 256, 256, 0, stream>>>(row, col, cnt, dinv, csr_cw, e);
    transpose_both_kernel<<<(F * F + 40 * F + 255) / 256, 256, 0, stream>>>(W1, W2, wt1, wt2);
    convert_bf_kernel<<<(n * 64 + 255) / 256, 256, 0, stream>>>(x, xbf, n * 64);

    int gblk = (n + 63) / 64;  // 782

    // ---- layer 1: gather(x) -> z; h = relu(z@wt1 + b1); alpha2 = sigmoid(h.aw2+ab2) ----
    gather_kernel<<<(n + 3) / 4, 256, 0, stream>>>(x, xbf, rowStart, csr_cw, dinv,
                                                   aw1, ab1, zlp, n);
    gemm_kernel<128, 32, 8, true, true, true><<<gblk, 256, 0, stream>>>(
        zlp, wt1, b1, hbuf, aw2, ab2, alpha2, n);

    // ---- layer 2 (reordered): y = h@wt2; out = mix_rows(y) + b2 ----
    float* ybuf = zlp;  // reuse
    gemm_kernel<40, 10, 2, false, false, false><<<gblk, 320, 0, stream>>>(
        hbuf, wt2, nullptr, ybuf, nullptr, nullptr, nullptr, n);
    gather40_kernel<<<(n + 3) / 4, 256, 0, stream>>>(ybuf, rowStart, csr_cw, dinv,
                                                     alpha2, b2, out, n);
}